// Round 10
// baseline (92.231 us; speedup 1.0000x reference)
//
#include <hip/hip_runtime.h>

#define EPSF 1e-6f
#define L2E  1.44269504088896340736f   // log2(e)

using bf16x8 = __attribute__((ext_vector_type(8))) short;  // 8 bf16 (4 VGPRs)
using f32x16 = __attribute__((ext_vector_type(16))) float;

constexpr int NT    = 256;
constexpr int JC    = 256;               // q columns per block
constexpr int NJC   = 8192 / JC;         // 32 chunks
constexpr int RPAN  = 256;               // z rows per block (4 waves x 2 bands x 32)
constexpr int NRP   = 16384 / RPAN;      // 64 row panels
constexpr int NB    = NRP * NJC;         // 2048 blocks (single assignment, 8/CU)
constexpr int JT    = JC / 32;           // 8 j-tiles per chunk
constexpr int RSTRB = 20;                // B row stride in shorts (40B padded)

// RNE float -> bf16 (as short), and back
__device__ __forceinline__ short f2bf(float f) {
    union { float f; unsigned u; } c{f};
    return (short)((c.u + 0x7fffu + ((c.u >> 16) & 1u)) >> 16);
}
__device__ __forceinline__ float bf2f(short s) {
    union { unsigned u; float f; } c{((unsigned)(unsigned short)s) << 16};
    return c.f;
}

// ---------------------------------------------------------------------------
__device__ __forceinline__ float block_reduce_sum(float v) {
#pragma unroll
    for (int off = 32; off > 0; off >>= 1) v += __shfl_down(v, off, 64);
    __shared__ float parts[4];
    const int t = threadIdx.x;
    if ((t & 63) == 0) parts[t >> 6] = v;
    __syncthreads();
    float r = 0.f;
    if (t == 0) r = parts[0] + parts[1] + parts[2] + parts[3];
    return r;
}

// Build augmented A-frag for one z row straight from global.
// half 0: [zh_0..zh_7]; half 1: [zn, 1, 0...]  (zh = bf16(L2E*(z+eps)))
__device__ __forceinline__ bf16x8 make_afrag(const float* __restrict__ z,
                                             int row, int half) {
    const float4 a = *(const float4*)(z + (size_t)row * 8);
    const float4 b = *(const float4*)(z + (size_t)row * 8 + 4);
    const float h[8] = {L2E * (a.x + EPSF), L2E * (a.y + EPSF),
                        L2E * (a.z + EPSF), L2E * (a.w + EPSF),
                        L2E * (b.x + EPSF), L2E * (b.y + EPSF),
                        L2E * (b.z + EPSF), L2E * (b.w + EPSF)};
    short s[8];
    float zn = 0.f;
#pragma unroll
    for (int d = 0; d < 8; ++d) {
        s[d] = f2bf(h[d]);
        const float r = bf2f(s[d]);
        zn = fmaf(r, r, zn);
    }
    bf16x8 f;
    if (half == 0) {
        f[0] = s[0]; f[1] = s[1]; f[2] = s[2]; f[3] = s[3];
        f[4] = s[4]; f[5] = s[5]; f[6] = s[6]; f[7] = s[7];
    } else {
        f[0] = f2bf(zn); f[1] = (short)0x3F80;
        f[2] = 0; f[3] = 0; f[4] = 0; f[5] = 0; f[6] = 0; f[7] = 0;
    }
    return f;
}

// ---------------------------------------------------------------------------
// Dense: K=10 augmented 32x32x16 MFMA emits D = L2E^2*dist^2 directly.
//   A row i = [zh, zn_i, 1, 0...] ; B col j = [-2qh, 1, qn_j, 0...]
//   term = 2^(sld_j - sqrt(D)), sld = L2E*(delta-eps); weight exp(gamma) at end.
// Each wave: 2 row-bands (2 MFMAs per B-frag). Sparse phase parity-staggered.
// ---------------------------------------------------------------------------
__global__ __launch_bounds__(NT) void fused_kernel(
    const float* __restrict__ z, const float* __restrict__ q,
    const float* __restrict__ gamma, const float* __restrict__ delta,
    const float* __restrict__ w, const int* __restrict__ si,
    const int* __restrict__ sj, int nnz, float* __restrict__ partial)
{
    __shared__ short sqb[JC * RSTRB];  // 10KB B-side cols (padded)
    __shared__ float sld[JC];          // 1KB  L2E*(delta - eps)
    __shared__ float seg[RPAN];        // 1KB  exp(gamma)

    const int t      = threadIdx.x;
    const int id     = blockIdx.x;
    const int jc     = id & (NJC - 1);
    const int rpan   = id >> 5;            // id / NJC
    const int c0     = jc * JC;
    const int r0base = rpan * RPAN;

    // ---- stage B col t + sld + seg (one col/row per thread) ----
    {
        seg[t] = __expf(gamma[r0base + t]);
        const int C = c0 + t;
        const float4 a = *(const float4*)(q + (size_t)C * 8);
        const float4 b = *(const float4*)(q + (size_t)C * 8 + 4);
        const float h[8] = {L2E * a.x, L2E * a.y, L2E * a.z, L2E * a.w,
                            L2E * b.x, L2E * b.y, L2E * b.z, L2E * b.w};
        float qn = 0.f;
#pragma unroll
        for (int d = 0; d < 8; ++d) {
            const short s = f2bf(h[d]);
            const float r = bf2f(s);
            qn = fmaf(r, r, qn);
            sqb[t * RSTRB + d] = f2bf(-2.f * r);  // exact: -2x is exponent shift
        }
        sqb[t * RSTRB + 8] = (short)0x3F80;       // 1.0 bf16
        sqb[t * RSTRB + 9] = f2bf(qn);
#pragma unroll
        for (int d = 10; d < 16; ++d) sqb[t * RSTRB + d] = 0;
        sld[t] = L2E * (delta[C] - EPSF);
    }

    // ---- sparse slice (exact fp32), parity-staggered ----
    float sacc = 0.f;
    if ((id & 1) == 0) {
        for (int k = id * NT + t; k < nnz; k += NB * NT) {
            const int i = si[k];
            const int j = sj[k];
            const float4 a = *(const float4*)(z + (size_t)i * 8);
            const float4 b = *(const float4*)(z + (size_t)i * 8 + 4);
            const float4 c = *(const float4*)(q + (size_t)j * 8);
            const float4 d = *(const float4*)(q + (size_t)j * 8 + 4);
            const float d0 = a.x - c.x + EPSF, d1 = a.y - c.y + EPSF;
            const float d2 = a.z - c.z + EPSF, d3 = a.w - c.w + EPSF;
            const float d4 = b.x - d.x + EPSF, d5 = b.y - d.y + EPSF;
            const float d6 = b.z - d.z + EPSF, d7 = b.w - d.w + EPSF;
            float s2 = d0 * d0;
            s2 = fmaf(d1, d1, s2); s2 = fmaf(d2, d2, s2); s2 = fmaf(d3, d3, s2);
            s2 = fmaf(d4, d4, s2); s2 = fmaf(d5, d5, s2); s2 = fmaf(d6, d6, s2);
            s2 = fmaf(d7, d7, s2);
            sacc = fmaf(w[k], gamma[i] + delta[j] - __builtin_amdgcn_sqrtf(s2), sacc);
        }
    }
    __syncthreads();

    // ---- per-wave: 2 bands x 8 j-tiles ----
    const int wv   = t >> 6;
    const int lane = t & 63;
    const int li   = lane & 31;
    const int half = lane >> 5;

    const bf16x8 af0 = make_afrag(z, r0base + wv * 32 + li, half);
    const bf16x8 af1 = make_afrag(z, r0base + 128 + wv * 32 + li, half);

    float acc0[16], acc1[16];
#pragma unroll
    for (int r = 0; r < 16; ++r) { acc0[r] = 0.f; acc1[r] = 0.f; }

#pragma unroll
    for (int jt = 0; jt < JT; ++jt) {
        const bf16x8 bfrag = *(const bf16x8*)&sqb[(jt * 32 + li) * RSTRB + half * 8];
        const float  ld_l  = sld[jt * 32 + li];
        {
            f32x16 s = __builtin_amdgcn_mfma_f32_32x32x16_bf16(
                af0, bfrag, (f32x16)(0.f), 0, 0, 0);
#pragma unroll
            for (int r = 0; r < 16; ++r) {
                const float st = __builtin_amdgcn_sqrtf(__builtin_fabsf(s[r]));
                acc0[r] += __builtin_amdgcn_exp2f(ld_l - st);
            }
        }
        {
            f32x16 s = __builtin_amdgcn_mfma_f32_32x32x16_bf16(
                af1, bfrag, (f32x16)(0.f), 0, 0, 0);
#pragma unroll
            for (int r = 0; r < 16; ++r) {
                const float st = __builtin_amdgcn_sqrtf(__builtin_fabsf(s[r]));
                acc1[r] += __builtin_amdgcn_exp2f(ld_l - st);
            }
        }
    }

    // weight by exp(gamma_row); row = band + wv*32 + 4*half + (r&3) + 8*(r>>2)
    float vv = 0.f;
#pragma unroll
    for (int r4 = 0; r4 < 4; ++r4)
#pragma unroll
        for (int r0 = 0; r0 < 4; ++r0) {
            const int rr = wv * 32 + half * 4 + r0 + 8 * r4;
            vv = fmaf(seg[rr],       acc0[r4 * 4 + r0], vv);
            vv = fmaf(seg[128 + rr], acc1[r4 * 4 + r0], vv);
        }

    // ---- odd blocks: sparse after dense ----
    if (id & 1) {
        for (int k = id * NT + t; k < nnz; k += NB * NT) {
            const int i = si[k];
            const int j = sj[k];
            const float4 a = *(const float4*)(z + (size_t)i * 8);
            const float4 b = *(const float4*)(z + (size_t)i * 8 + 4);
            const float4 c = *(const float4*)(q + (size_t)j * 8);
            const float4 d = *(const float4*)(q + (size_t)j * 8 + 4);
            const float d0 = a.x - c.x + EPSF, d1 = a.y - c.y + EPSF;
            const float d2 = a.z - c.z + EPSF, d3 = a.w - c.w + EPSF;
            const float d4 = b.x - d.x + EPSF, d5 = b.y - d.y + EPSF;
            const float d6 = b.z - d.z + EPSF, d7 = b.w - d.w + EPSF;
            float s2 = d0 * d0;
            s2 = fmaf(d1, d1, s2); s2 = fmaf(d2, d2, s2); s2 = fmaf(d3, d3, s2);
            s2 = fmaf(d4, d4, s2); s2 = fmaf(d5, d5, s2); s2 = fmaf(d6, d6, s2);
            s2 = fmaf(d7, d7, s2);
            sacc = fmaf(w[k], gamma[i] + delta[j] - __builtin_amdgcn_sqrtf(s2), sacc);
        }
    }

    const float v = block_reduce_sum(sacc - vv);
    if (t == 0) partial[id] = v;
}

// ---------------------------------------------------------------------------
__global__ __launch_bounds__(256) void reduce_kernel(
    const float* __restrict__ partial, int n, float* __restrict__ out)
{
    float v = 0.f;
    for (int k = threadIdx.x; k < n; k += 256) v += partial[k];
    v = block_reduce_sum(v);
    if (threadIdx.x == 0) out[0] = v;
}

// ---------------------------------------------------------------------------
extern "C" void kernel_launch(void* const* d_in, const int* in_sizes, int n_in,
                              void* d_out, int out_size, void* d_ws, size_t ws_size,
                              hipStream_t stream) {
    const float* z     = (const float*)d_in[0];   // [16384, 8]
    const float* q     = (const float*)d_in[1];   // [8192, 8]
    const float* gamma = (const float*)d_in[2];   // [16384]
    const float* delta = (const float*)d_in[3];   // [8192]
    const float* w     = (const float*)d_in[4];   // [nnz]
    const int*   si    = (const int*)d_in[5];     // [nnz]
    const int*   sj    = (const int*)d_in[6];     // [nnz]
    const int    nnz   = in_sizes[4];

    float* out = (float*)d_out;
    float* ws  = (float*)d_ws;

    fused_kernel<<<NB, NT, 0, stream>>>(z, q, gamma, delta, w, si, sj, nnz, ws);
    reduce_kernel<<<1, 256, 0, stream>>>(ws, NB, out);
}

// Round 11
// 48.028 us; speedup vs baseline: 1.9204x; 1.9204x over previous
//
#include <hip/hip_runtime.h>

#define EPSF 1e-6f
#define L2E  1.44269504088896340736f   // log2(e)

using bf16x8 = __attribute__((ext_vector_type(8))) short;  // 8 bf16 (4 VGPRs)
using f32x16 = __attribute__((ext_vector_type(16))) float;

constexpr int NT   = 256;
constexpr int JC   = 512;               // q columns per block
constexpr int NJC  = 8192 / JC;         // 16 chunks
constexpr int RPAN = 128;               // z rows per block (4 waves x 32)
constexpr int NRP  = 16384 / RPAN;      // 128 row panels
constexpr int NB   = NRP * NJC;         // 2048 blocks (8/CU, full wave slots)
constexpr int JT   = JC / 32;           // 16 j-tiles per chunk
constexpr int RSTR = 16;                // B row stride in shorts (32B, unpadded)

// RNE float -> bf16 (as short), and back
__device__ __forceinline__ short f2bf(float f) {
    union { float f; unsigned u; } c{f};
    return (short)((c.u + 0x7fffu + ((c.u >> 16) & 1u)) >> 16);
}
__device__ __forceinline__ float bf2f(short s) {
    union { unsigned u; float f; } c{((unsigned)(unsigned short)s) << 16};
    return c.f;
}

// ---------------------------------------------------------------------------
__device__ __forceinline__ float block_reduce_sum(float v) {
#pragma unroll
    for (int off = 32; off > 0; off >>= 1) v += __shfl_down(v, off, 64);
    __shared__ float parts[4];
    const int t = threadIdx.x;
    if ((t & 63) == 0) parts[t >> 6] = v;
    __syncthreads();
    float r = 0.f;
    if (t == 0) r = parts[0] + parts[1] + parts[2] + parts[3];
    return r;
}

// Augmented A-frag for one z row straight from global (L2-resident).
// half 0: [zh_0..zh_7]; half 1: [zn, 1, 0...]  (zh = bf16(L2E*(z+eps)))
__device__ __forceinline__ bf16x8 make_afrag(const float* __restrict__ z,
                                             int row, int half) {
    const float4 a = *(const float4*)(z + (size_t)row * 8);
    const float4 b = *(const float4*)(z + (size_t)row * 8 + 4);
    const float h[8] = {L2E * (a.x + EPSF), L2E * (a.y + EPSF),
                        L2E * (a.z + EPSF), L2E * (a.w + EPSF),
                        L2E * (b.x + EPSF), L2E * (b.y + EPSF),
                        L2E * (b.z + EPSF), L2E * (b.w + EPSF)};
    short s[8];
    float zn = 0.f;
#pragma unroll
    for (int d = 0; d < 8; ++d) {
        s[d] = f2bf(h[d]);
        const float r = bf2f(s[d]);
        zn = fmaf(r, r, zn);
    }
    bf16x8 f;
    if (half == 0) {
        f[0] = s[0]; f[1] = s[1]; f[2] = s[2]; f[3] = s[3];
        f[4] = s[4]; f[5] = s[5]; f[6] = s[6]; f[7] = s[7];
    } else {
        f[0] = f2bf(zn); f[1] = (short)0x3F80;
        f[2] = 0; f[3] = 0; f[4] = 0; f[5] = 0; f[6] = 0; f[7] = 0;
    }
    return f;
}

// ---------------------------------------------------------------------------
// Dense: K=10 augmented 32x32x16 MFMA emits D = L2E^2*dist^2 directly.
//   A row i = [zh, zn_i, 1, 0...] ; B col j = [-2qh, 1, qn_j, 0...]
//   term = 2^(sld_j - sqrt(D)); weight exp(gamma_i) at the end.
// One band per wave (acc=16 regs, VGPR<=64); A built per-lane from global
// (no A-LDS, no A staging convoy); 16 tiles of pure epilogue per barrier.
// ---------------------------------------------------------------------------
__global__ __launch_bounds__(NT) void fused_kernel(
    const float* __restrict__ z, const float* __restrict__ q,
    const float* __restrict__ gamma, const float* __restrict__ delta,
    const float* __restrict__ w, const int* __restrict__ si,
    const int* __restrict__ sj, int nnz, float* __restrict__ partial)
{
    __shared__ short sqb[JC * RSTR];  // 16KB B-side cols
    __shared__ float sld[JC];         // 2KB  L2E*(delta - eps)
    __shared__ float seg[RPAN];       // 512B exp(gamma)

    const int t      = threadIdx.x;
    const int id     = blockIdx.x;
    const int jc     = id & (NJC - 1);
    const int rpan   = id >> 4;          // id / NJC
    const int c0     = jc * JC;
    const int r0base = rpan * RPAN;

    // ---- stage B cols (2 per thread) + sld; seg for the 128 rows ----
    if (t < RPAN) seg[t] = __expf(gamma[r0base + t]);
#pragma unroll
    for (int c = t; c < JC; c += NT) {
        const int C = c0 + c;
        const float4 a = *(const float4*)(q + (size_t)C * 8);
        const float4 b = *(const float4*)(q + (size_t)C * 8 + 4);
        const float h[8] = {L2E * a.x, L2E * a.y, L2E * a.z, L2E * a.w,
                            L2E * b.x, L2E * b.y, L2E * b.z, L2E * b.w};
        float qn = 0.f;
#pragma unroll
        for (int d = 0; d < 8; ++d) {
            const short s = f2bf(h[d]);
            const float r = bf2f(s);
            qn = fmaf(r, r, qn);
            sqb[c * RSTR + d] = f2bf(-2.f * r);  // exact: -2x is exponent shift
        }
        sqb[c * RSTR + 8] = (short)0x3F80;       // 1.0 bf16
        sqb[c * RSTR + 9] = f2bf(qn);
#pragma unroll
        for (int d = 10; d < 16; ++d) sqb[c * RSTR + d] = 0;
        sld[c] = L2E * (delta[C] - EPSF);
    }

    // ---- A-frag per lane (only 4 VGPRs live across sparse) ----
    const int wv   = t >> 6;
    const int lane = t & 63;
    const int li   = lane & 31;
    const int half = lane >> 5;
    const bf16x8 afrag = make_afrag(z, r0base + wv * 32 + li, half);

    // ---- sparse slice (exact fp32) ----
    float sacc = 0.f;
    for (int k = id * NT + t; k < nnz; k += NB * NT) {
        const int i = si[k];
        const int j = sj[k];
        const float4 a = *(const float4*)(z + (size_t)i * 8);
        const float4 b = *(const float4*)(z + (size_t)i * 8 + 4);
        const float4 c = *(const float4*)(q + (size_t)j * 8);
        const float4 d = *(const float4*)(q + (size_t)j * 8 + 4);
        const float d0 = a.x - c.x + EPSF, d1 = a.y - c.y + EPSF;
        const float d2 = a.z - c.z + EPSF, d3 = a.w - c.w + EPSF;
        const float d4 = b.x - d.x + EPSF, d5 = b.y - d.y + EPSF;
        const float d6 = b.z - d.z + EPSF, d7 = b.w - d.w + EPSF;
        float s2 = d0 * d0;
        s2 = fmaf(d1, d1, s2); s2 = fmaf(d2, d2, s2); s2 = fmaf(d3, d3, s2);
        s2 = fmaf(d4, d4, s2); s2 = fmaf(d5, d5, s2); s2 = fmaf(d6, d6, s2);
        s2 = fmaf(d7, d7, s2);
        sacc = fmaf(w[k], gamma[i] + delta[j] - __builtin_amdgcn_sqrtf(s2), sacc);
    }
    __syncthreads();

    // ---- dense: 16 j-tiles, pure epilogue between barriers ----
    float acc[16];
#pragma unroll
    for (int r = 0; r < 16; ++r) acc[r] = 0.f;

#pragma unroll
    for (int jt = 0; jt < JT; ++jt) {
        const bf16x8 bfrag = *(const bf16x8*)&sqb[(jt * 32 + li) * RSTR + half * 8];
        const float  ld_l  = sld[jt * 32 + li];
        f32x16 s = __builtin_amdgcn_mfma_f32_32x32x16_bf16(
            afrag, bfrag, (f32x16)(0.f), 0, 0, 0);
#pragma unroll
        for (int r = 0; r < 16; ++r) {
            const float st = __builtin_amdgcn_sqrtf(__builtin_fabsf(s[r]));
            acc[r] += __builtin_amdgcn_exp2f(ld_l - st);
        }
    }

    // weight by exp(gamma_row); row = wv*32 + 4*half + (r&3) + 8*(r>>2)
    float vv = 0.f;
#pragma unroll
    for (int r4 = 0; r4 < 4; ++r4)
#pragma unroll
        for (int r0 = 0; r0 < 4; ++r0)
            vv = fmaf(seg[wv * 32 + half * 4 + r0 + 8 * r4], acc[r4 * 4 + r0], vv);

    const float v = block_reduce_sum(sacc - vv);
    if (t == 0) partial[id] = v;
}

// ---------------------------------------------------------------------------
__global__ __launch_bounds__(256) void reduce_kernel(
    const float* __restrict__ partial, int n, float* __restrict__ out)
{
    float v = 0.f;
    for (int k = threadIdx.x; k < n; k += 256) v += partial[k];
    v = block_reduce_sum(v);
    if (threadIdx.x == 0) out[0] = v;
}

// ---------------------------------------------------------------------------
extern "C" void kernel_launch(void* const* d_in, const int* in_sizes, int n_in,
                              void* d_out, int out_size, void* d_ws, size_t ws_size,
                              hipStream_t stream) {
    const float* z     = (const float*)d_in[0];   // [16384, 8]
    const float* q     = (const float*)d_in[1];   // [8192, 8]
    const float* gamma = (const float*)d_in[2];   // [16384]
    const float* delta = (const float*)d_in[3];   // [8192]
    const float* w     = (const float*)d_in[4];   // [nnz]
    const int*   si    = (const int*)d_in[5];     // [nnz]
    const int*   sj    = (const int*)d_in[6];     // [nnz]
    const int    nnz   = in_sizes[4];

    float* out = (float*)d_out;
    float* ws  = (float*)d_ws;

    fused_kernel<<<NB, NT, 0, stream>>>(z, q, gamma, delta, w, si, sj, nnz, ws);
    reduce_kernel<<<1, 256, 0, stream>>>(ws, NB, out);
}